// Round 2
// baseline (10079.861 us; speedup 1.0000x reference)
//
#include <hip/hip_runtime.h>

// LSTM_36807869726767 — round 1: f32 I/O (round-0 NaN proved inputs are f32,
// not bf16). MFMA via _Float16 hi/lo splits: 3-term (f32-class accuracy) for
// the sequential h-recurrence, 1-term for input-transform & energy GEMMs.
// B=64, S=512, E=512, H=1024, NCLS=10, PAD=0.

typedef _Float16 f16;
typedef __attribute__((ext_vector_type(8))) _Float16 f16x8;
typedef __attribute__((ext_vector_type(4))) _Float16 f16x4;
typedef __attribute__((ext_vector_type(4))) float f32x4;

#define Bn 64
#define Sn 512
#define En 512
#define Hn 1024
#define CHUNK 64   // timesteps per pre-GEMM chunk

// ------------------------------------------------------------- weight splits
// Wg f32 [4096][1536] -> hi/lo f16
__global__ __launch_bounds__(256) void split_wg_k(
    const float* __restrict__ Wg, f16* __restrict__ hi, f16* __restrict__ lo)
{
    size_t g = ((size_t)blockIdx.x * 256 + threadIdx.x) * 8;  // < 6291456
    float4 a = *(const float4*)&Wg[g];
    float4 b = *(const float4*)&Wg[g + 4];
    f16x8 h, l;
    float v[8] = {a.x, a.y, a.z, a.w, b.x, b.y, b.z, b.w};
    #pragma unroll
    for (int i = 0; i < 8; ++i) {
        f16 hv = (f16)v[i];
        h[i] = hv;
        l[i] = (f16)(v[i] - (float)hv);
    }
    *(f16x8*)&hi[g] = h;
    *(f16x8*)&lo[g] = l;
}

// Wa f32 [1024][1024] -> hi f16 only (single-term energy GEMM)
__global__ __launch_bounds__(256) void split_wa_k(
    const float* __restrict__ Wa, f16* __restrict__ hi)
{
    size_t g = ((size_t)blockIdx.x * 256 + threadIdx.x) * 8;  // < 1048576
    float4 a = *(const float4*)&Wa[g];
    float4 b = *(const float4*)&Wa[g + 4];
    f16x8 h;
    float v[8] = {a.x, a.y, a.z, a.w, b.x, b.y, b.z, b.w};
    #pragma unroll
    for (int i = 0; i < 8; ++i) h[i] = (f16)v[i];
    *(f16x8*)&hi[g] = h;
}

// ------------------------------------------------- gather e chunk (f16 hi)
// e_ch[m][k], m = t_local*64 + b, k<512 : emb[x[b,c*64+t_local]][k]
__global__ __launch_bounds__(256) void gather_chunk_k(
    const int* __restrict__ x, const float* __restrict__ emb,
    f16* __restrict__ e_ch, int c)
{
    size_t g = (size_t)blockIdx.x * 256 + threadIdx.x;   // 262144
    int m  = (int)(g >> 6);          // 0..4095
    int ko = (int)(g & 63) * 8;
    int b  = m & 63, tl = m >> 6;
    int tok = x[b * Sn + c * CHUNK + tl];
    float4 a = *(const float4*)&emb[(size_t)tok * En + ko];
    float4 bb = *(const float4*)&emb[(size_t)tok * En + ko + 4];
    f16x8 h;
    float v[8] = {a.x, a.y, a.z, a.w, bb.x, bb.y, bb.z, bb.w};
    #pragma unroll
    for (int i = 0; i < 8; ++i) h[i] = (f16)v[i];
    *(f16x8*)&e_ch[(size_t)m * En + ko] = h;
}

// ------------------------------------------------- input-transform pre-GEMM
// G_in[m][j] = sum_k e_ch[m][k] * Wg[j][k] + bg[j]   (k<512, f16 single-term)
__global__ __launch_bounds__(256) void pregemm_k(
    const f16* __restrict__ e_ch,   // [4096][512]
    const f16* __restrict__ Wg_hi,  // [4096][1536] (cols 0..511 used)
    const float* __restrict__ bg,   // [4096]
    float* __restrict__ G_in)       // [4096][4096]
{
    __shared__ f16 Ws[128][136];
    const int bid = blockIdx.x;
    const int rb = bid >> 5;        // 64 row-blocks of 64
    const int nb = bid & 31;        // 32 col-blocks of 128
    const int tid = threadIdx.x;
    const int lane = tid & 63, w = tid >> 6, cl = lane & 15, q = lane >> 4;
    const int r0 = rb * 64 + w * 16 + cl;

    f32x4 acc[8];
    #pragma unroll
    for (int i = 0; i < 8; ++i) acc[i] = (f32x4){0.f, 0.f, 0.f, 0.f};

    for (int kc = 0; kc < 4; ++kc) {      // 4 chunks of 128 k
        __syncthreads();
        for (int i = tid; i < 128 * 16; i += 256) {
            int dd = i >> 4;
            int kv = (i & 15) * 8;
            *(f16x8*)&Ws[dd][kv] =
                *(const f16x8*)&Wg_hi[(size_t)(nb * 128 + dd) * 1536 + kc * 128 + kv];
        }
        __syncthreads();
        const f16* A = e_ch + (size_t)r0 * En + kc * 128;
        #pragma unroll
        for (int ks = 0; ks < 4; ++ks) {
            f16x8 a = *(const f16x8*)&A[ks * 32 + q * 8];
            #pragma unroll
            for (int nt = 0; nt < 8; ++nt) {
                f16x8 bb = *(const f16x8*)&Ws[nt * 16 + cl][ks * 32 + q * 8];
                acc[nt] = __builtin_amdgcn_mfma_f32_16x16x32_f16(a, bb, acc[nt], 0, 0, 0);
            }
        }
    }
    // store + bias. D: row = q*4+r, col = nt*16+cl
    #pragma unroll
    for (int nt = 0; nt < 8; ++nt) {
        int j = nb * 128 + nt * 16 + cl;
        float bgv = bg[j];
        #pragma unroll
        for (int r = 0; r < 4; ++r) {
            int m = rb * 64 + w * 16 + q * 4 + r;
            G_in[(size_t)m * 4096 + j] = acc[nt][r] + bgv;
        }
    }
}

// ---------------------------------------------------------------- LSTM step
// 256 blocks; block bk owns cells d0=bk*4 (16 gate rows). 3-term f16 h-GEMM.
__global__ __launch_bounds__(256) void lstm_step_k(
    const float* __restrict__ G_in,   // [CHUNK][64][4096] (e-part + bg)
    const f16* __restrict__ Wg_hi, const f16* __restrict__ Wg_lo, // [4096][1536]
    const f16* __restrict__ hin_hi, const f16* __restrict__ hin_lo, // [64][H]
    f16* __restrict__ hout_hi, f16* __restrict__ hout_lo,
    float* __restrict__ c_st,                                       // [64][H]
    f16* __restrict__ hs_hi, f16* __restrict__ hs_lo,               // [64*S][H]
    int t, int t_local)
{
    __shared__ f16 Wsh[16][1032];
    __shared__ f16 Wsl[16][1032];
    const int tid = threadIdx.x;
    const int bk  = blockIdx.x;
    const int d0  = bk * 4;

    { // stage W h-part rows (cols 512..1535): n -> j = (n>>2)*1024 + d0 + (n&3)
        int n = tid >> 4, c16 = tid & 15;
        int j = (n >> 2) * 1024 + d0 + (n & 3);
        const f16* sh = Wg_hi + (size_t)j * 1536 + 512;
        const f16* sl = Wg_lo + (size_t)j * 1536 + 512;
        for (int kk = c16 * 8; kk < 1024; kk += 128) {
            *(f16x8*)&Wsh[n][kk] = *(const f16x8*)&sh[kk];
            *(f16x8*)&Wsl[n][kk] = *(const f16x8*)&sl[kk];
        }
    }
    __syncthreads();

    const int lane = tid & 63;
    const int w    = tid >> 6;
    const int cl   = lane & 15;
    const int q    = lane >> 4;
    const int b    = w * 16 + cl;
    const int koff = q * 8;

    const f16* Ah = hin_hi + (size_t)b * Hn;
    const f16* Al = hin_lo + (size_t)b * Hn;

    f32x4 acc = {0.f, 0.f, 0.f, 0.f};
    #pragma unroll 4
    for (int ks = 0; ks < 32; ++ks) {
        f16x8 ah = *(const f16x8*)&Ah[ks * 32 + koff];
        f16x8 al = *(const f16x8*)&Al[ks * 32 + koff];
        f16x8 bh = *(const f16x8*)&Wsh[cl][ks * 32 + koff];
        f16x8 bl = *(const f16x8*)&Wsl[cl][ks * 32 + koff];
        acc = __builtin_amdgcn_mfma_f32_16x16x32_f16(ah, bh, acc, 0, 0, 0);
        acc = __builtin_amdgcn_mfma_f32_16x16x32_f16(ah, bl, acc, 0, 0, 0);
        acc = __builtin_amdgcn_mfma_f32_16x16x32_f16(al, bh, acc, 0, 0, 0);
    }

    // add input transform (includes bias). D: row=q*4+r (batch-16), col=cl.
    const int jcol = (cl >> 2) * 1024 + d0 + (cl & 3);
    const float* Gt = G_in + (size_t)t_local * 64 * 4096;
    #pragma unroll
    for (int r = 0; r < 4; ++r)
        acc[r] += Gt[(size_t)(w * 16 + q * 4 + r) * 4096 + jcol];

    // gate exchange + cell update. cols: 0..3=i, 4..7=f, 8..11=g, 12..15=o.
    const int L = lane, co = cl & 3;
    #pragma unroll
    for (int r = 0; r < 4; ++r) {
        float av = acc[r];
        float iv = __shfl(av, (L & 48) | co,      64);
        float fv = __shfl(av, (L & 48) | 4 | co,  64);
        float gv = __shfl(av, (L & 48) | 8 | co,  64);
        float ov = __shfl(av, (L & 48) | 12 | co, 64);
        if (cl < 4) {
            int d  = d0 + co;
            int br = w * 16 + q * 4 + r;
            float i_ = 1.f / (1.f + expf(-iv));
            float f_ = 1.f / (1.f + expf(-fv));
            float g_ = tanhf(gv);
            float o_ = 1.f / (1.f + expf(-ov));
            size_t ci = (size_t)br * Hn + d;
            float cn = f_ * c_st[ci] + i_ * g_;
            c_st[ci] = cn;
            float hn = o_ * tanhf(cn);
            f16 hh = (f16)hn;
            f16 hl = (f16)(hn - (float)hh);
            hout_hi[ci] = hh; hout_lo[ci] = hl;
            size_t si = ((size_t)br * Sn + t) * Hn + d;
            hs_hi[si] = hh; hs_lo[si] = hl;
        }
    }
}

// ---------------------------------------------------------------- energy GEMM
// energy[row] += sum_{d in block} tanh(sum_k hs[row,k]*Wa[d,k]) * va[d]
__global__ __launch_bounds__(256) void energy_k(
    const f16* __restrict__ hs_hi,   // [B*S][H]
    const f16* __restrict__ Wa_hi,   // [H][H]
    const float* __restrict__ va,    // [H]
    float* __restrict__ energy)      // [B*S], pre-zeroed
{
    __shared__ f16 Was[128][136];
    const int bid = blockIdx.x;
    const int rb = bid >> 3;        // 512 row-blocks of 64
    const int nb = bid & 7;         // 8 col-blocks of 128
    const int tid = threadIdx.x;
    const int lane = tid & 63, w = tid >> 6, cl = lane & 15, q = lane >> 4;
    const int r0 = rb * 64 + w * 16 + cl;

    f32x4 acc[8];
    #pragma unroll
    for (int i = 0; i < 8; ++i) acc[i] = (f32x4){0.f, 0.f, 0.f, 0.f};

    for (int kc = 0; kc < 8; ++kc) {
        __syncthreads();
        for (int i = tid; i < 128 * 16; i += 256) {
            int dd = i >> 4;
            int kv = (i & 15) * 8;
            *(f16x8*)&Was[dd][kv] =
                *(const f16x8*)&Wa_hi[(size_t)(nb * 128 + dd) * Hn + kc * 128 + kv];
        }
        __syncthreads();
        const f16* A = hs_hi + (size_t)r0 * Hn + kc * 128;
        #pragma unroll
        for (int ks = 0; ks < 4; ++ks) {
            f16x8 a = *(const f16x8*)&A[ks * 32 + q * 8];
            #pragma unroll
            for (int nt = 0; nt < 8; ++nt) {
                f16x8 bb = *(const f16x8*)&Was[nt * 16 + cl][ks * 32 + q * 8];
                acc[nt] = __builtin_amdgcn_mfma_f32_16x16x32_f16(a, bb, acc[nt], 0, 0, 0);
            }
        }
    }

    float rowsum[4] = {0.f, 0.f, 0.f, 0.f};
    #pragma unroll
    for (int nt = 0; nt < 8; ++nt) {
        float vv = va[nb * 128 + nt * 16 + cl];
        #pragma unroll
        for (int r = 0; r < 4; ++r)
            rowsum[r] += tanhf(acc[nt][r]) * vv;
    }
    #pragma unroll
    for (int m = 1; m < 16; m <<= 1)
        #pragma unroll
        for (int r = 0; r < 4; ++r)
            rowsum[r] += __shfl_xor(rowsum[r], m, 64);
    if (cl == 0) {
        #pragma unroll
        for (int r = 0; r < 4; ++r)
            atomicAdd(&energy[(size_t)rb * 64 + w * 16 + q * 4 + r], rowsum[r]);
    }
}

// ------------------------------------------------- masked softmax + context
__global__ __launch_bounds__(256) void softctx_k(
    const float* __restrict__ energy, const int* __restrict__ x,
    const f16* __restrict__ hs_hi, const f16* __restrict__ hs_lo,
    float* __restrict__ context)   // [B][H]
{
    __shared__ float sm[512];
    __shared__ float red[256];
    const int b = blockIdx.x, tid = threadIdx.x;
    const int s0 = tid, s1 = tid + 256;
    float e0 = (x[b * Sn + s0] != 0) ? energy[b * Sn + s0] : -1e10f;
    float e1 = (x[b * Sn + s1] != 0) ? energy[b * Sn + s1] : -1e10f;
    red[tid] = fmaxf(e0, e1);
    __syncthreads();
    for (int st = 128; st > 0; st >>= 1) {
        if (tid < st) red[tid] = fmaxf(red[tid], red[tid + st]);
        __syncthreads();
    }
    float M = red[0];
    __syncthreads();
    float p0 = expf(e0 - M), p1 = expf(e1 - M);
    red[tid] = p0 + p1;
    __syncthreads();
    for (int st = 128; st > 0; st >>= 1) {
        if (tid < st) red[tid] += red[tid + st];
        __syncthreads();
    }
    float inv = 1.f / red[0];
    sm[s0] = p0 * inv; sm[s1] = p1 * inv;
    __syncthreads();

    const int d0v = tid * 4;
    float a0 = 0.f, a1 = 0.f, a2 = 0.f, a3 = 0.f;
    const f16* Hh = hs_hi + (size_t)b * Sn * Hn + d0v;
    const f16* Hl = hs_lo + (size_t)b * Sn * Hn + d0v;
    for (int s = 0; s < Sn; ++s) {
        float at = sm[s];
        f16x4 vh = *(const f16x4*)&Hh[(size_t)s * Hn];
        f16x4 vl = *(const f16x4*)&Hl[(size_t)s * Hn];
        a0 += at * ((float)vh[0] + (float)vl[0]);
        a1 += at * ((float)vh[1] + (float)vl[1]);
        a2 += at * ((float)vh[2] + (float)vl[2]);
        a3 += at * ((float)vh[3] + (float)vl[3]);
    }
    float* cp = context + (size_t)b * Hn + d0v;
    cp[0] = a0; cp[1] = a1; cp[2] = a2; cp[3] = a3;
}

// ---------------------------------------------------------------- logits
__global__ __launch_bounds__(256) void logits_k(
    const float* __restrict__ context, const float* __restrict__ WV,
    const float* __restrict__ bV, float* __restrict__ out)
{
    __shared__ float red[10][257];
    const int b = blockIdx.x, tid = threadIdx.x;
    const int d0v = tid * 4;
    float4 cv = *(const float4*)&context[(size_t)b * Hn + d0v];
    #pragma unroll
    for (int cls = 0; cls < 10; ++cls) {
        float4 wv = *(const float4*)&WV[cls * Hn + d0v];
        red[cls][tid] = cv.x * wv.x + cv.y * wv.y + cv.z * wv.z + cv.w * wv.w;
    }
    __syncthreads();
    for (int st = 128; st > 0; st >>= 1) {
        if (tid < st)
            #pragma unroll
            for (int cls = 0; cls < 10; ++cls)
                red[cls][tid] += red[cls][tid + st];
        __syncthreads();
    }
    if (tid < 10) out[b * 10 + tid] = red[tid][0] + bV[tid];
}

// ---------------------------------------------------------------- launch
extern "C" void kernel_launch(void* const* d_in, const int* in_sizes, int n_in,
                              void* d_out, int out_size, void* d_ws, size_t ws_size,
                              hipStream_t stream)
{
    const int*   x   = (const int*)d_in[0];
    const float* emb = (const float*)d_in[1];
    const float* Wg  = (const float*)d_in[2];
    const float* bg  = (const float*)d_in[3];
    const float* Wa  = (const float*)d_in[4];
    const float* va  = (const float*)d_in[5];
    const float* WV  = (const float*)d_in[6];
    const float* bV  = (const float*)d_in[7];
    float* out = (float*)d_out;

    char* ws = (char*)d_ws;
    size_t o = 0;
    auto alloc = [&](size_t bytes) { void* p = ws + o; o += (bytes + 255) & ~(size_t)255; return p; };
    f16*   Wg_hi = (f16*)alloc((size_t)4096 * 1536 * 2);
    f16*   Wg_lo = (f16*)alloc((size_t)4096 * 1536 * 2);
    f16*   Wa_hi = (f16*)alloc((size_t)1024 * 1024 * 2);
    f16*   e_ch  = (f16*)alloc((size_t)4096 * 512 * 2);
    float* G_in  = (float*)alloc((size_t)4096 * 4096 * 4);     // 67 MB
    f16*   h0h   = (f16*)alloc((size_t)Bn * Hn * 2);
    f16*   h0l   = (f16*)alloc((size_t)Bn * Hn * 2);
    f16*   h1h   = (f16*)alloc((size_t)Bn * Hn * 2);
    f16*   h1l   = (f16*)alloc((size_t)Bn * Hn * 2);
    float* c_st  = (float*)alloc((size_t)Bn * Hn * 4);
    f16*   hs_hi = (f16*)alloc((size_t)Bn * Sn * Hn * 2);      // 67 MB
    f16*   hs_lo = (f16*)alloc((size_t)Bn * Sn * Hn * 2);      // 67 MB
    float* energy= (float*)alloc((size_t)Bn * Sn * 4);
    float* ctx   = (float*)alloc((size_t)Bn * Hn * 4);
    // total ~221 MB

    hipMemsetAsync(h0h, 0, (size_t)Bn * Hn * 2, stream);
    hipMemsetAsync(h0l, 0, (size_t)Bn * Hn * 2, stream);
    hipMemsetAsync(c_st, 0, (size_t)Bn * Hn * 4, stream);
    hipMemsetAsync(energy, 0, (size_t)Bn * Sn * 4, stream);

    split_wg_k<<<3072, 256, 0, stream>>>(Wg, Wg_hi, Wg_lo);
    split_wa_k<<<512, 256, 0, stream>>>(Wa, Wa_hi);

    const f16 *hih = h0h, *hil = h0l;
    f16 *hoh = h1h, *hol = h1l;
    for (int c = 0; c < Sn / CHUNK; ++c) {
        gather_chunk_k<<<1024, 256, 0, stream>>>(x, emb, e_ch, c);
        pregemm_k<<<64 * 32, 256, 0, stream>>>(e_ch, Wg_hi, bg, G_in);
        for (int tl = 0; tl < CHUNK; ++tl) {
            lstm_step_k<<<256, 256, 0, stream>>>(G_in, Wg_hi, Wg_lo,
                                                 hih, hil, hoh, hol,
                                                 c_st, hs_hi, hs_lo,
                                                 c * CHUNK + tl, tl);
            const f16* th = hoh; const f16* tl2 = hol;
            hoh = (f16*)hih; hol = (f16*)hil;
            hih = th; hil = tl2;
        }
    }

    energy_k<<<512 * 8, 256, 0, stream>>>(hs_hi, Wa_hi, va, energy);
    softctx_k<<<Bn, 256, 0, stream>>>(energy, x, hs_hi, hs_lo, ctx);
    logits_k<<<Bn, 256, 0, stream>>>(ctx, WV, bV, out);
}